// Round 4
// baseline (216.745 us; speedup 1.0000x reference)
//
#include <hip/hip_runtime.h>

// Problem constants (fixed by reference)
#define B_ 4
#define T_ 4096
#define D_ 256
#define H_ 64
#define NBT (B_ * T_)         // 16384
#define NBTH (B_ * T_ * H_)   // 1048576

typedef __bf16 bf16x8 __attribute__((ext_vector_type(8)));
typedef float f32x4 __attribute__((ext_vector_type(4)));

__device__ __forceinline__ unsigned short f2bf(float f) {
  union { float f; unsigned int u; } v; v.f = f;
  unsigned int u = v.u;
  return (unsigned short)((u + 0x7fffu + ((u >> 16) & 1u)) >> 16);  // RNE
}

#if __has_builtin(__builtin_amdgcn_cvt_pk_bf16_f32)
typedef __bf16 bf16x2_t __attribute__((ext_vector_type(2)));
__device__ __forceinline__ unsigned int pk2(float a, float b) {
  union { bf16x2_t v; unsigned int u; } c;
  c.v = __builtin_amdgcn_cvt_pk_bf16_f32(a, b);   // lo = a, hi = b
  return c.u;
}
#else
__device__ __forceinline__ unsigned int pk2(float a, float b) {
  return (unsigned int)f2bf(a) | ((unsigned int)f2bf(b) << 16);
}
#endif

#if __has_builtin(__builtin_amdgcn_exp2f)
#define EXP2(x) __builtin_amdgcn_exp2f(x)
#else
#define EXP2(x) exp2f(x)
#endif

// log2(e)/16 — folds the 1/sqrt(256) logit scale AND exp->exp2 into Wq
// (RoPE rotation is linear: scale commutes).
#define QSCALE 0.09016844f

// ===========================================================================
// FRAGMENT-ORDERED GLOBAL LAYOUTS: every MFMA operand fragment
// (64 lanes x 16 B) is stored contiguously, so consumers issue
// perfectly-coalesced global b128 loads with NO LDS staging and NO barriers.
//   W:  wfrag(m, ht, c)        = ((m*4+ht)*8+c)*512    + lane*8
//   Q:  qfrag(rowblk16, half)  = (rowblk*2+half)*512   + lane*8
//   K:  kfrag(kvblk64,mt,half) = ((kvblk*4+mt)*2+half)*512 + lane*8
//   V:  vfrag(kvblk64,hh,half) = ((kvblk*4+hh)*2+half)*512 + lane*8
// (rowblk/kvblk are GLOBAL over B*T; lane = quad*16+l16.)
//
// ROUND-3 POST-MORTEM (kept as a warning): cooperative LDS staging of K/V
// with 2 s_barriers + counted vmcnt per tile took attn 15 -> 132 us
// (MfmaUtil 4.9%).  With ~64 MFMA/wave/tile of compute and 2 blocks/CU,
// lockstepping the waves exposes the full load+sync latency serially per
// tile (m233-class structural stall).  The barrier-free form below keeps
// all 8 waves/CU independent so they slip and hide each other's latency.
// ===========================================================================

// ---------------------------------------------------------------------------
// Kernel P: W transpose + bf16 cast + fragment-order emit. 12 blocks.
// Also zeroes the split-KV finisher counters (must precede attn in-stream;
// re-runs every iteration, which re-arms the counters after ws re-poison).
// ---------------------------------------------------------------------------
__global__ __launch_bounds__(256) void prep_w_kernel(
    const float* __restrict__ Wq, const float* __restrict__ Wk,
    const float* __restrict__ Wv, unsigned short* __restrict__ wt,
    int* __restrict__ cnt) {
  if (blockIdx.x == 0 && threadIdx.x < 64) cnt[threadIdx.x] = 0;
  const int m = blockIdx.x >> 2;        // 0..2: which matrix
  const int cp = blockIdx.x & 3;        // c-pair: handles c = cp*2, cp*2+1
  const float* W = (m == 0) ? Wq : (m == 1) ? Wk : Wv;
  const float scale = (m == 0) ? QSCALE : 1.f;
  __shared__ __align__(16) unsigned short tile[64][72];  // [h][d-local]
  int h = threadIdx.x & 63, dq = threadIdx.x >> 6;
  const int d0 = cp * 64;
  for (int dl = dq; dl < 64; dl += 4)
    tile[h][dl] = f2bf(W[(d0 + dl) * H_ + h] * scale);
  __syncthreads();
  int ht = threadIdx.x >> 6;            // wave = ht
  int lane = threadIdx.x & 63, quad = lane >> 4, l16 = lane & 15;
#pragma unroll
  for (int cl = 0; cl < 2; ++cl) {
    int c = cp * 2 + cl;
    bf16x8 v = *(const bf16x8*)&tile[ht * 16 + l16][cl * 32 + quad * 8];
    *(bf16x8*)&wt[(((m * 4 + ht) * 8 + c) << 9) + lane * 8] = v;
  }
}

// ---------------------------------------------------------------------------
// Kernel A: MFMA QKV projection + RoPE, fragment-ordered outputs.
// (unchanged from round 2)
// ---------------------------------------------------------------------------
__global__ __launch_bounds__(192) void qkv_kernel(
    const float* __restrict__ x, const unsigned short* __restrict__ wt,
    const float* __restrict__ axg, const float* __restrict__ ayg,
    unsigned short* __restrict__ qo, unsigned short* __restrict__ ko,
    unsigned short* __restrict__ vt) {
  const int row0g = blockIdx.x * 16;    // global flat row over B*T
  const int tid = threadIdx.x;
  const int w = tid / 64, lane = tid & 63, quad = lane >> 4, l16 = lane & 15;

  __shared__ unsigned short xs[16][264];      // 8.4 KB
  __shared__ unsigned short qkt[2][16][72];   // q/k transpose, per-wave
  __shared__ unsigned short vsh[64][16];      // v transpose (wave 2 only)

  // stage x-tile: 16 rows x 256 f32 = 1024 float4, convert to bf16
  const float4* xb = (const float4*)(x + (size_t)row0g * D_);
  for (int i = tid; i < 1024; i += 192) {
    float4 v = xb[i];
    int r = i >> 6, c4 = (i & 63) << 2;
    *(unsigned int*)&xs[r][c4] = pk2(v.x, v.y);
    *(unsigned int*)&xs[r][c4 + 2] = pk2(v.z, v.w);
  }
  __syncthreads();

  // x fragments: A[m=l16][k=c*32+quad*8+j]
  bf16x8 xf[8];
#pragma unroll
  for (int c = 0; c < 8; ++c)
    xf[c] = *(const bf16x8*)&xs[l16][c * 32 + quad * 8];

  // GEMM for matrix w: W-frags coalesced from global
  const unsigned short* wb = wt + (((size_t)w * 4) * 8 << 9);
  f32x4 acc[4];
#pragma unroll
  for (int ht = 0; ht < 4; ++ht) acc[ht] = (f32x4){0.f, 0.f, 0.f, 0.f};
#pragma unroll
  for (int c = 0; c < 8; ++c) {
#pragma unroll
    for (int ht = 0; ht < 4; ++ht) {
      bf16x8 wf = *(const bf16x8*)&wb[((ht * 8 + c) << 9) + lane * 8];
      acc[ht] = __builtin_amdgcn_mfma_f32_16x16x32_bf16(xf[c], wf, acc[ht],
                                                        0, 0, 0);
    }
  }

  const int row0loc = row0g & (T_ - 1);
  if (w < 2) {
    // RoPE on C/D layout, then LDS transpose -> fragment-order store
    const float sgn = (l16 & 1) ? 1.f : -1.f;
#pragma unroll
    for (int ht = 0; ht < 4; ++ht) {
      int hh = ht * 16 + l16;
      int pidx = (hh & 31) >> 1;
      const float* ab = (hh >= 32) ? ayg : axg;
#pragma unroll
      for (int r = 0; r < 4; ++r) {
        int t = row0loc + quad * 4 + r;
        float s, c;
        __sincosf(ab[t * 16 + pidx], &s, &c);
        float val = acc[ht][r];
        float par = __shfl_xor(val, 1);   // RoPE pair partner h^1
        qkt[w][quad * 4 + r][hh] = f2bf(val * c + sgn * par * s);
      }
    }
    asm volatile("s_waitcnt lgkmcnt(0)" ::: "memory");  // intra-wave
    unsigned short* dst;
    size_t base;
    if (w == 0) {
      dst = qo;
      base = ((size_t)(row0g >> 4) * 2) << 9;
    } else {
      dst = ko;
      base = ((size_t)((row0g >> 6) * 8 + ((row0g >> 4) & 3) * 2)) << 9;
    }
#pragma unroll
    for (int half = 0; half < 2; ++half) {
      bf16x8 v = *(const bf16x8*)&qkt[w][l16][half * 32 + quad * 8];
      *(bf16x8*)&dst[base + half * 512 + lane * 8] = v;
    }
  } else {
    // v: C/D -> LDS transpose -> partial fragment-order store
#pragma unroll
    for (int ht = 0; ht < 4; ++ht)
#pragma unroll
      for (int r = 0; r < 4; ++r)
        vsh[ht * 16 + l16][quad * 4 + r] = f2bf(acc[ht][r]);
    asm volatile("s_waitcnt lgkmcnt(0)" ::: "memory");  // intra-wave
    const int kvblk = row0g >> 6;       // global 64-blk
    const int mt = (row0g >> 4) & 3;
    const int half_v = mt >> 1, qlow = (mt & 1) * 2;
#pragma unroll
    for (int it = 0; it < 2; ++it) {
      int hhx = it * 2 + (quad >> 1);
      int qp = qlow + (quad & 1);
      bf16x8 v = *(const bf16x8*)&vsh[hhx * 16 + l16][(quad & 1) * 8];
      *(bf16x8*)&vt[((((size_t)kvblk * 4 + hhx) * 2 + half_v) << 9) +
                    (qp * 16 + l16) * 8] = v;
    }
  }
}

// ---------------------------------------------------------------------------
// Kernel B: flash attention, split-KV, fixed max (logits bounded; m=0
// softmax is exact math), exp2 domain.  Round-2 barrier-free structure
// (reverted from round-3's disastrous LDS-staging lockstep):
//  * each wave owns 64 q-rows (u=0..3), block owns 256; 512 blocks, 2/CU,
//    8 independent waves/CU — no inter-wave sync anywhere in the main loop.
//  * V loads (current tile) + K prefetch (next tile) issued BEFORE the
//    lgkmcnt(0) Ps drain, hiding L2 latency under exp2/pack + PV MFMAs.
// Round-4 single delta: combine FUSED as split-K finisher — after partial
// writes, threadfence + device-scope atomic counter; the last split block
// for each (b,q0) chunk normalizes its 256 rows (partials L3-warm).
// ---------------------------------------------------------------------------
#define LDP 72

__global__ __launch_bounds__(256, 2) void attn_kernel(
    const unsigned short* __restrict__ qfg, const unsigned short* __restrict__ kfg,
    const unsigned short* __restrict__ vfg, float* __restrict__ opart,
    float* __restrict__ lpart, int* __restrict__ cnt, float* __restrict__ out,
    int kv_len) {
  const int split = blockIdx.x >> 6;    // 64 blocks per split
  const int rem = blockIdx.x & 63;
  const int b = rem >> 4;
  const int q0 = (rem & 15) * 256;
  const int tid = threadIdx.x;
  const int w = tid >> 6, lane = tid & 63, quad = lane >> 4, l16 = lane & 15;

  __shared__ unsigned short Ps[4][64 * LDP];   // per-wave P, 36 KB
  __shared__ int last_flag;

  // Q fragments (B-operand), coalesced from fragment-ordered qfg
  bf16x8 qf[4][2];
#pragma unroll
  for (int u = 0; u < 4; ++u) {
    size_t rb = (size_t)(b * T_ + q0 + w * 64 + u * 16) >> 4;
#pragma unroll
    for (int half = 0; half < 2; ++half)
      qf[u][half] = *(const bf16x8*)&qfg[((rb * 2 + half) << 9) + lane * 8];
  }

  f32x4 oacc[4][4];
  float lsum[4] = {0.f, 0.f, 0.f, 0.f};
  const f32x4 vzero = {0.f, 0.f, 0.f, 0.f};
#pragma unroll
  for (int u = 0; u < 4; ++u)
#pragma unroll
    for (int hh = 0; hh < 4; ++hh) oacc[u][hh] = vzero;

  const int kvb0 = (b * T_ + split * kv_len) >> 6;
  const int nkvb = kv_len >> 6;

  // prologue: K fragments for tile 0
  bf16x8 kf[8];
  {
    const unsigned short* kfb = kfg + ((size_t)kvb0 << 12);
#pragma unroll
    for (int f = 0; f < 8; ++f)
      kf[f] = *(const bf16x8*)&kfb[(f << 9) + lane * 8];
  }

  for (int kb = 0; kb < nkvb; ++kb) {
    const unsigned short* vfb = vfg + ((size_t)(kvb0 + kb) << 12);
    const int kbn = (kb + 1 < nkvb) ? (kb + 1) : kb;
    const unsigned short* kfb_n = kfg + ((size_t)(kvb0 + kbn) << 12);

    // S^T: D[kv=mt*16+quad*4+r][q=u*16+l16] (log2 domain via QSCALE),
    // exp2 + pack + LDS write fused per (mt,u); l accumulated on VALU.
#pragma unroll
    for (int mt = 0; mt < 4; ++mt) {
#pragma unroll
      for (int u = 0; u < 4; ++u) {
        f32x4 s = vzero;
        s = __builtin_amdgcn_mfma_f32_16x16x32_bf16(kf[mt * 2 + 0], qf[u][0],
                                                    s, 0, 0, 0);
        s = __builtin_amdgcn_mfma_f32_16x16x32_bf16(kf[mt * 2 + 1], qf[u][1],
                                                    s, 0, 0, 0);
        float p0 = EXP2(s[0]);
        float p1 = EXP2(s[1]);
        float p2 = EXP2(s[2]);
        float p3 = EXP2(s[3]);
        lsum[u] += (p0 + p1) + (p2 + p3);
        uint2 pk;
        pk.x = pk2(p0, p1);
        pk.y = pk2(p2, p3);
        *(uint2*)&Ps[w][(u * 16 + l16) * LDP + mt * 16 + quad * 4] = pk;
      }
    }

    // issue V loads (current tile) + K prefetch (next tile) BEFORE the LDS
    // drain — vmcnt traffic overlaps the Ps round-trip and PV MFMAs.
    bf16x8 vf[8];
#pragma unroll
    for (int f = 0; f < 8; ++f)
      vf[f] = *(const bf16x8*)&vfb[(f << 9) + lane * 8];
#pragma unroll
    for (int f = 0; f < 8; ++f)
      kf[f] = *(const bf16x8*)&kfb_n[(f << 9) + lane * 8];

    asm volatile("s_waitcnt lgkmcnt(0)" ::: "memory");  // intra-wave Ps

    bf16x8 ap[4][2];
#pragma unroll
    for (int u = 0; u < 4; ++u)
#pragma unroll
      for (int half = 0; half < 2; ++half)
        ap[u][half] =
            *(const bf16x8*)&Ps[w][(u * 16 + l16) * LDP + half * 32 + quad * 8];

#pragma unroll
    for (int hh = 0; hh < 4; ++hh) {
#pragma unroll
      for (int u = 0; u < 4; ++u) {
        oacc[u][hh] = __builtin_amdgcn_mfma_f32_16x16x32_bf16(
            ap[u][0], vf[hh * 2 + 0], oacc[u][hh], 0, 0, 0);
        oacc[u][hh] = __builtin_amdgcn_mfma_f32_16x16x32_bf16(
            ap[u][1], vf[hh * 2 + 1], oacc[u][hh], 0, 0, 0);
      }
    }
  }

  // epilogue: un-normalized partials; l via lane butterfly (sum over quads)
#pragma unroll
  for (int u = 0; u < 4; ++u) {
    size_t base = (size_t)(split * B_ + b) * T_ + q0 + w * 64 + u * 16;
#pragma unroll
    for (int r = 0; r < 4; ++r) {
      float* orow = opart + (base + quad * 4 + r) * H_;
#pragma unroll
      for (int hh = 0; hh < 4; ++hh) orow[hh * 16 + l16] = oacc[u][hh][r];
    }
    float l = lsum[u];
    l += __shfl_xor(l, 16);
    l += __shfl_xor(l, 32);
    if (quad == 0) lpart[base + l16] = l;   // coalesced 16-wide
  }

  // fused combine: last split block for this (b,q0) chunk normalizes.
  __threadfence();                          // release partials (device scope)
  if (tid == 0) {
    int old = atomicAdd(&cnt[rem], 1);
    last_flag = (old == (int)(gridDim.x >> 6) - 1);
  }
  __syncthreads();
  if (last_flag) {
    __threadfence();                        // acquire: see all splits' writes
    const int ns = gridDim.x >> 6;
    for (int i = tid; i < 256 * 16; i += 256) {
      int r = i >> 4, h4 = i & 15;
      size_t row = (size_t)b * T_ + q0 + r;
      float den = 0.f;
      float ax = 0.f, ay = 0.f, az = 0.f, aw = 0.f;
      for (int s = 0; s < ns; ++s) {
        den += lpart[(size_t)s * NBT + row];
        float4 o = *(const float4*)&opart[((size_t)s * NBT + row) * H_ + h4 * 4];
        ax += o.x; ay += o.y; az += o.z; aw += o.w;
      }
      float inv = 1.f / den;
      float4 res;
      res.x = ax * inv; res.y = ay * inv; res.z = az * inv; res.w = aw * inv;
      *(float4*)&out[row * H_ + h4 * 4] = res;
    }
  }
}

// ---------------------------------------------------------------------------
extern "C" void kernel_launch(void* const* d_in, const int* in_sizes, int n_in,
                              void* d_out, int out_size, void* d_ws,
                              size_t ws_size, hipStream_t stream) {
  const float* x  = (const float*)d_in[0];
  const float* Wq = (const float*)d_in[1];
  const float* Wk = (const float*)d_in[2];
  const float* Wv = (const float*)d_in[3];
  const float* ax = (const float*)d_in[4];
  const float* ay = (const float*)d_in[5];
  float* out = (float*)d_out;

  // ws: q|k|v frag-ordered bf16 (6MB) | wt bf16 (96KB) | opart | lpart | cnt
  unsigned short* qo = (unsigned short*)d_ws;
  unsigned short* ko = qo + NBTH;
  unsigned short* vt = ko + NBTH;
  unsigned short* wt = vt + NBTH;
  float* opart = (float*)(wt + 3 * H_ * D_);

  size_t fixed = (size_t)3 * NBTH * 2 + (size_t)3 * H_ * D_ * 2;
  int NS = (ws_size >= fixed + (size_t)8 * NBTH * 4 + (size_t)8 * NBT * 4 + 512)
               ? 8 : 4;
  float* lpart = opart + (size_t)NS * NBTH;
  int* cnt = (int*)(lpart + (size_t)NS * NBT);

  prep_w_kernel<<<12, 256, 0, stream>>>(Wq, Wk, Wv, wt, cnt);
  qkv_kernel<<<NBT / 16, 192, 0, stream>>>(x, wt, ax, ay, qo, ko, vt);
  attn_kernel<<<NS * 64, 256, 0, stream>>>(qo, ko, vt, opart, lpart, cnt, out,
                                           T_ / NS);
}

// Round 7
// 113.075 us; speedup vs baseline: 1.9168x; 1.9168x over previous
//
#include <hip/hip_runtime.h>

// Problem constants (fixed by reference)
#define B_ 4
#define T_ 4096
#define D_ 256
#define H_ 64
#define NBT (B_ * T_)         // 16384
#define NBTH (B_ * T_ * H_)   // 1048576

typedef __bf16 bf16x8 __attribute__((ext_vector_type(8)));
typedef float f32x4 __attribute__((ext_vector_type(4)));

__device__ __forceinline__ unsigned short f2bf(float f) {
  union { float f; unsigned int u; } v; v.f = f;
  unsigned int u = v.u;
  return (unsigned short)((u + 0x7fffu + ((u >> 16) & 1u)) >> 16);  // RNE
}

#if __has_builtin(__builtin_amdgcn_cvt_pk_bf16_f32)
typedef __bf16 bf16x2_t __attribute__((ext_vector_type(2)));
__device__ __forceinline__ unsigned int pk2(float a, float b) {
  union { bf16x2_t v; unsigned int u; } c;
  c.v = __builtin_amdgcn_cvt_pk_bf16_f32(a, b);   // lo = a, hi = b
  return c.u;
}
#else
__device__ __forceinline__ unsigned int pk2(float a, float b) {
  return (unsigned int)f2bf(a) | ((unsigned int)f2bf(b) << 16);
}
#endif

#if __has_builtin(__builtin_amdgcn_exp2f)
#define EXP2(x) __builtin_amdgcn_exp2f(x)
#else
#define EXP2(x) exp2f(x)
#endif

// log2(e)/16 — folds the 1/sqrt(256) logit scale AND exp->exp2 into Wq
// (RoPE rotation is linear: scale commutes).
#define QSCALE 0.09016844f

// ===========================================================================
// FRAGMENT-ORDERED GLOBAL LAYOUTS: every MFMA operand fragment
// (64 lanes x 16 B) is stored contiguously, so consumers issue
// perfectly-coalesced global b128 loads with NO LDS staging and NO barriers.
//   W:  wfrag(m, ht, c)        = ((m*4+ht)*8+c)*512    + lane*8
//   Q:  qfrag(rowblk16, half)  = (rowblk*2+half)*512   + lane*8
//   K:  kfrag(kvblk64,mt,half) = ((kvblk*4+mt)*2+half)*512 + lane*8
//   V:  vfrag(kvblk64,hh,half) = ((kvblk*4+hh)*2+half)*512 + lane*8
// (rowblk/kvblk are GLOBAL over B*T; lane = quad*16+l16.)
//
// SESSION WARNINGS (hard-won):
//  * R3: cooperative LDS staging w/ per-tile s_barriers -> attn 15->132 us.
//    With only ~64 MFMA/wave/tile, lockstepped waves expose the full
//    load+sync latency.  Keep the loop barrier-FREE; independent waves
//    hide each other's latency.
//  * R4: __threadfence() (device-scope) in attn -> attn 140 us.  On
//    multi-XCD CDNA a device fence = L2 writeback/invalidate maintenance;
//    512 of them nuke K/V L2 residency chip-wide (FETCH 34 MB, Mfma 4.7%).
//    NO device fences in hot kernels; split-K combine stays a separate
//    kernel.
//  * R5/R6: container infra failures (broker-level; source audited clean —
//    bounded loops, in-bounds indexing).  This is the same source, third
//    submission: the XCD-matched-combine delta is still unmeasured.
// ===========================================================================

// ---------------------------------------------------------------------------
// Kernel P: W transpose + bf16 cast + fragment-order emit. 12 blocks.
// ---------------------------------------------------------------------------
__global__ __launch_bounds__(256) void prep_w_kernel(
    const float* __restrict__ Wq, const float* __restrict__ Wk,
    const float* __restrict__ Wv, unsigned short* __restrict__ wt) {
  const int m = blockIdx.x >> 2;        // 0..2: which matrix
  const int cp = blockIdx.x & 3;        // c-pair: handles c = cp*2, cp*2+1
  const float* W = (m == 0) ? Wq : (m == 1) ? Wk : Wv;
  const float scale = (m == 0) ? QSCALE : 1.f;
  __shared__ __align__(16) unsigned short tile[64][72];  // [h][d-local]
  int h = threadIdx.x & 63, dq = threadIdx.x >> 6;
  const int d0 = cp * 64;
  for (int dl = dq; dl < 64; dl += 4)
    tile[h][dl] = f2bf(W[(d0 + dl) * H_ + h] * scale);
  __syncthreads();
  int ht = threadIdx.x >> 6;            // wave = ht
  int lane = threadIdx.x & 63, quad = lane >> 4, l16 = lane & 15;
#pragma unroll
  for (int cl = 0; cl < 2; ++cl) {
    int c = cp * 2 + cl;
    bf16x8 v = *(const bf16x8*)&tile[ht * 16 + l16][cl * 32 + quad * 8];
    *(bf16x8*)&wt[(((m * 4 + ht) * 8 + c) << 9) + lane * 8] = v;
  }
}

// ---------------------------------------------------------------------------
// Kernel A: MFMA QKV projection + RoPE, fragment-ordered outputs.
// (unchanged from round 2)
// ---------------------------------------------------------------------------
__global__ __launch_bounds__(192) void qkv_kernel(
    const float* __restrict__ x, const unsigned short* __restrict__ wt,
    const float* __restrict__ axg, const float* __restrict__ ayg,
    unsigned short* __restrict__ qo, unsigned short* __restrict__ ko,
    unsigned short* __restrict__ vt) {
  const int row0g = blockIdx.x * 16;    // global flat row over B*T
  const int tid = threadIdx.x;
  const int w = tid / 64, lane = tid & 63, quad = lane >> 4, l16 = lane & 15;

  __shared__ unsigned short xs[16][264];      // 8.4 KB
  __shared__ unsigned short qkt[2][16][72];   // q/k transpose, per-wave
  __shared__ unsigned short vsh[64][16];      // v transpose (wave 2 only)

  // stage x-tile: 16 rows x 256 f32 = 1024 float4, convert to bf16
  const float4* xb = (const float4*)(x + (size_t)row0g * D_);
  for (int i = tid; i < 1024; i += 192) {
    float4 v = xb[i];
    int r = i >> 6, c4 = (i & 63) << 2;
    *(unsigned int*)&xs[r][c4] = pk2(v.x, v.y);
    *(unsigned int*)&xs[r][c4 + 2] = pk2(v.z, v.w);
  }
  __syncthreads();

  // x fragments: A[m=l16][k=c*32+quad*8+j]
  bf16x8 xf[8];
#pragma unroll
  for (int c = 0; c < 8; ++c)
    xf[c] = *(const bf16x8*)&xs[l16][c * 32 + quad * 8];

  // GEMM for matrix w: W-frags coalesced from global
  const unsigned short* wb = wt + (((size_t)w * 4) * 8 << 9);
  f32x4 acc[4];
#pragma unroll
  for (int ht = 0; ht < 4; ++ht) acc[ht] = (f32x4){0.f, 0.f, 0.f, 0.f};
#pragma unroll
  for (int c = 0; c < 8; ++c) {
#pragma unroll
    for (int ht = 0; ht < 4; ++ht) {
      bf16x8 wf = *(const bf16x8*)&wb[((ht * 8 + c) << 9) + lane * 8];
      acc[ht] = __builtin_amdgcn_mfma_f32_16x16x32_bf16(xf[c], wf, acc[ht],
                                                        0, 0, 0);
    }
  }

  const int row0loc = row0g & (T_ - 1);
  if (w < 2) {
    // RoPE on C/D layout, then LDS transpose -> fragment-order store
    const float sgn = (l16 & 1) ? 1.f : -1.f;
#pragma unroll
    for (int ht = 0; ht < 4; ++ht) {
      int hh = ht * 16 + l16;
      int pidx = (hh & 31) >> 1;
      const float* ab = (hh >= 32) ? ayg : axg;
#pragma unroll
      for (int r = 0; r < 4; ++r) {
        int t = row0loc + quad * 4 + r;
        float s, c;
        __sincosf(ab[t * 16 + pidx], &s, &c);
        float val = acc[ht][r];
        float par = __shfl_xor(val, 1);   // RoPE pair partner h^1
        qkt[w][quad * 4 + r][hh] = f2bf(val * c + sgn * par * s);
      }
    }
    asm volatile("s_waitcnt lgkmcnt(0)" ::: "memory");  // intra-wave
    unsigned short* dst;
    size_t base;
    if (w == 0) {
      dst = qo;
      base = ((size_t)(row0g >> 4) * 2) << 9;
    } else {
      dst = ko;
      base = ((size_t)((row0g >> 6) * 8 + ((row0g >> 4) & 3) * 2)) << 9;
    }
#pragma unroll
    for (int half = 0; half < 2; ++half) {
      bf16x8 v = *(const bf16x8*)&qkt[w][l16][half * 32 + quad * 8];
      *(bf16x8*)&dst[base + half * 512 + lane * 8] = v;
    }
  } else {
    // v: C/D -> LDS transpose -> partial fragment-order store
#pragma unroll
    for (int ht = 0; ht < 4; ++ht)
#pragma unroll
      for (int r = 0; r < 4; ++r)
        vsh[ht * 16 + l16][quad * 4 + r] = f2bf(acc[ht][r]);
    asm volatile("s_waitcnt lgkmcnt(0)" ::: "memory");  // intra-wave
    const int kvblk = row0g >> 6;       // global 64-blk
    const int mt = (row0g >> 4) & 3;
    const int half_v = mt >> 1, qlow = (mt & 1) * 2;
#pragma unroll
    for (int it = 0; it < 2; ++it) {
      int hhx = it * 2 + (quad >> 1);
      int qp = qlow + (quad & 1);
      bf16x8 v = *(const bf16x8*)&vsh[hhx * 16 + l16][(quad & 1) * 8];
      *(bf16x8*)&vt[((((size_t)kvblk * 4 + hhx) * 2 + half_v) << 9) +
                    (qp * 16 + l16) * 8] = v;
    }
  }
}

// ---------------------------------------------------------------------------
// Kernel B: flash attention, split-KV, fixed max (logits bounded; m=0
// softmax is exact math), exp2 domain.  EXACT round-2 structure (110.8 us
// total): barrier-free, each wave owns 64 q-rows (u=0..3), block owns 256;
// 512 blocks, 2/CU, 8 independent waves/CU.  V loads + next-K prefetch
// issued before the lgkmcnt(0) Ps drain.  No fences, no atomics.
// ---------------------------------------------------------------------------
#define LDP 72

__global__ __launch_bounds__(256, 2) void attn_kernel(
    const unsigned short* __restrict__ qfg, const unsigned short* __restrict__ kfg,
    const unsigned short* __restrict__ vfg, float* __restrict__ opart,
    float* __restrict__ lpart, int kv_len) {
  const int split = blockIdx.x >> 6;    // 64 blocks per split
  const int rem = blockIdx.x & 63;
  const int b = rem >> 4;
  const int q0 = (rem & 15) * 256;
  const int tid = threadIdx.x;
  const int w = tid >> 6, lane = tid & 63, quad = lane >> 4, l16 = lane & 15;

  __shared__ unsigned short Ps[4][64 * LDP];   // per-wave P, 36 KB

  // Q fragments (B-operand), coalesced from fragment-ordered qfg
  bf16x8 qf[4][2];
#pragma unroll
  for (int u = 0; u < 4; ++u) {
    size_t rb = (size_t)(b * T_ + q0 + w * 64 + u * 16) >> 4;
#pragma unroll
    for (int half = 0; half < 2; ++half)
      qf[u][half] = *(const bf16x8*)&qfg[((rb * 2 + half) << 9) + lane * 8];
  }

  f32x4 oacc[4][4];
  float lsum[4] = {0.f, 0.f, 0.f, 0.f};
  const f32x4 vzero = {0.f, 0.f, 0.f, 0.f};
#pragma unroll
  for (int u = 0; u < 4; ++u)
#pragma unroll
    for (int hh = 0; hh < 4; ++hh) oacc[u][hh] = vzero;

  const int kvb0 = (b * T_ + split * kv_len) >> 6;
  const int nkvb = kv_len >> 6;

  // prologue: K fragments for tile 0
  bf16x8 kf[8];
  {
    const unsigned short* kfb = kfg + ((size_t)kvb0 << 12);
#pragma unroll
    for (int f = 0; f < 8; ++f)
      kf[f] = *(const bf16x8*)&kfb[(f << 9) + lane * 8];
  }

  for (int kb = 0; kb < nkvb; ++kb) {
    const unsigned short* vfb = vfg + ((size_t)(kvb0 + kb) << 12);
    const int kbn = (kb + 1 < nkvb) ? (kb + 1) : kb;
    const unsigned short* kfb_n = kfg + ((size_t)(kvb0 + kbn) << 12);

    // S^T: D[kv=mt*16+quad*4+r][q=u*16+l16] (log2 domain via QSCALE),
    // exp2 + pack + LDS write fused per (mt,u); l accumulated on VALU.
#pragma unroll
    for (int mt = 0; mt < 4; ++mt) {
#pragma unroll
      for (int u = 0; u < 4; ++u) {
        f32x4 s = vzero;
        s = __builtin_amdgcn_mfma_f32_16x16x32_bf16(kf[mt * 2 + 0], qf[u][0],
                                                    s, 0, 0, 0);
        s = __builtin_amdgcn_mfma_f32_16x16x32_bf16(kf[mt * 2 + 1], qf[u][1],
                                                    s, 0, 0, 0);
        float p0 = EXP2(s[0]);
        float p1 = EXP2(s[1]);
        float p2 = EXP2(s[2]);
        float p3 = EXP2(s[3]);
        lsum[u] += (p0 + p1) + (p2 + p3);
        uint2 pk;
        pk.x = pk2(p0, p1);
        pk.y = pk2(p2, p3);
        *(uint2*)&Ps[w][(u * 16 + l16) * LDP + mt * 16 + quad * 4] = pk;
      }
    }

    // issue V loads (current tile) + K prefetch (next tile) BEFORE the LDS
    // drain — vmcnt traffic overlaps the Ps round-trip and PV MFMAs.
    bf16x8 vf[8];
#pragma unroll
    for (int f = 0; f < 8; ++f)
      vf[f] = *(const bf16x8*)&vfb[(f << 9) + lane * 8];
#pragma unroll
    for (int f = 0; f < 8; ++f)
      kf[f] = *(const bf16x8*)&kfb_n[(f << 9) + lane * 8];

    asm volatile("s_waitcnt lgkmcnt(0)" ::: "memory");  // intra-wave Ps

    bf16x8 ap[4][2];
#pragma unroll
    for (int u = 0; u < 4; ++u)
#pragma unroll
      for (int half = 0; half < 2; ++half)
        ap[u][half] =
            *(const bf16x8*)&Ps[w][(u * 16 + l16) * LDP + half * 32 + quad * 8];

#pragma unroll
    for (int hh = 0; hh < 4; ++hh) {
#pragma unroll
      for (int u = 0; u < 4; ++u) {
        oacc[u][hh] = __builtin_amdgcn_mfma_f32_16x16x32_bf16(
            ap[u][0], vf[hh * 2 + 0], oacc[u][hh], 0, 0, 0);
        oacc[u][hh] = __builtin_amdgcn_mfma_f32_16x16x32_bf16(
            ap[u][1], vf[hh * 2 + 1], oacc[u][hh], 0, 0, 0);
      }
    }
  }

  // epilogue: un-normalized partials; l via lane butterfly (sum over quads)
#pragma unroll
  for (int u = 0; u < 4; ++u) {
    size_t base = (size_t)(split * B_ + b) * T_ + q0 + w * 64 + u * 16;
#pragma unroll
    for (int r = 0; r < 4; ++r) {
      float* orow = opart + (base + quad * 4 + r) * H_;
#pragma unroll
      for (int hh = 0; hh < 4; ++hh) orow[hh * 16 + l16] = oacc[u][hh][r];
    }
    float l = lsum[u];
    l += __shfl_xor(l, 16);
    l += __shfl_xor(l, 32);
    if (quad == 0) lpart[base + l16] = l;   // coalesced 16-wide
  }
}

// ---------------------------------------------------------------------------
// Kernel C: out = (sum_s O_s) / (sum_s l_s).  XCD-matched block mapping:
// attn's 8 writers for chunk rem are blocks split*64+rem; since 64 % 8 == 0
// they all sit on XCD rem%8 (default %8 round-robin).  Reading block for
// chunk rem uses blockIdx == rem (mod 64) -> same XCD -> opart reads hit
// the local dirty L2 instead of resolving cross-XCD through L3/HBM.
// Grid 512: block = (j, rem), j = 32-row part of chunk.
// ---------------------------------------------------------------------------
__global__ __launch_bounds__(256) void combine_kernel(
    const float* __restrict__ opart, const float* __restrict__ lpart,
    float* __restrict__ out, int ns) {
  const int rem = blockIdx.x & 63;      // chunk, XCD-matched to attn writers
  const int j = blockIdx.x >> 6;        // 0..7: which 32-row part
  const size_t row0 = (size_t)(rem >> 4) * T_ + (rem & 15) * 256 + j * 32;
  const int t = threadIdx.x;
#pragma unroll
  for (int rep = 0; rep < 2; ++rep) {
    int idx = t + rep * 256;            // 0..511 float4s in this part
    int r = idx >> 4, c4 = idx & 15;
    size_t row = row0 + r;
    float den = 0.f;
    float ax = 0.f, ay = 0.f, az = 0.f, aw = 0.f;
    for (int s = 0; s < ns; ++s) {
      den += lpart[(size_t)s * NBT + row];
      float4 o = *(const float4*)&opart[((size_t)s * NBT + row) * H_ + c4 * 4];
      ax += o.x; ay += o.y; az += o.z; aw += o.w;
    }
    float inv = 1.f / den;
    float4 res;
    res.x = ax * inv; res.y = ay * inv; res.z = az * inv; res.w = aw * inv;
    *(float4*)&out[row * H_ + c4 * 4] = res;
  }
}

// ---------------------------------------------------------------------------
extern "C" void kernel_launch(void* const* d_in, const int* in_sizes, int n_in,
                              void* d_out, int out_size, void* d_ws,
                              size_t ws_size, hipStream_t stream) {
  const float* x  = (const float*)d_in[0];
  const float* Wq = (const float*)d_in[1];
  const float* Wk = (const float*)d_in[2];
  const float* Wv = (const float*)d_in[3];
  const float* ax = (const float*)d_in[4];
  const float* ay = (const float*)d_in[5];
  float* out = (float*)d_out;

  // ws: q|k|v frag-ordered bf16 (6MB) | wt bf16 (96KB) | opart | lpart
  unsigned short* qo = (unsigned short*)d_ws;
  unsigned short* ko = qo + NBTH;
  unsigned short* vt = ko + NBTH;
  unsigned short* wt = vt + NBTH;
  float* opart = (float*)(wt + 3 * H_ * D_);

  size_t fixed = (size_t)3 * NBTH * 2 + (size_t)3 * H_ * D_ * 2;
  int NS = (ws_size >= fixed + (size_t)8 * NBTH * 4 + (size_t)8 * NBT * 4 + 256)
               ? 8 : 4;
  float* lpart = opart + (size_t)NS * NBTH;

  prep_w_kernel<<<12, 256, 0, stream>>>(Wq, Wk, Wv, wt);
  qkv_kernel<<<NBT / 16, 192, 0, stream>>>(x, wt, ax, ay, qo, ko, vt);
  attn_kernel<<<NS * 64, 256, 0, stream>>>(qo, ko, vt, opart, lpart, T_ / NS);
  combine_kernel<<<512, 256, 0, stream>>>(opart, lpart, out, NS);
}

// Round 8
// 112.880 us; speedup vs baseline: 1.9201x; 1.0017x over previous
//
#include <hip/hip_runtime.h>

// Problem constants (fixed by reference)
#define B_ 4
#define T_ 4096
#define D_ 256
#define H_ 64
#define NBT (B_ * T_)         // 16384
#define NBTH (B_ * T_ * H_)   // 1048576

typedef __bf16 bf16x8 __attribute__((ext_vector_type(8)));
typedef float f32x4 __attribute__((ext_vector_type(4)));

__device__ __forceinline__ unsigned short f2bf(float f) {
  union { float f; unsigned int u; } v; v.f = f;
  unsigned int u = v.u;
  return (unsigned short)((u + 0x7fffu + ((u >> 16) & 1u)) >> 16);  // RNE
}

#if __has_builtin(__builtin_amdgcn_cvt_pk_bf16_f32)
typedef __bf16 bf16x2_t __attribute__((ext_vector_type(2)));
__device__ __forceinline__ unsigned int pk2(float a, float b) {
  union { bf16x2_t v; unsigned int u; } c;
  c.v = __builtin_amdgcn_cvt_pk_bf16_f32(a, b);   // lo = a, hi = b
  return c.u;
}
#else
__device__ __forceinline__ unsigned int pk2(float a, float b) {
  return (unsigned int)f2bf(a) | ((unsigned int)f2bf(b) << 16);
}
#endif

#if __has_builtin(__builtin_amdgcn_exp2f)
#define EXP2(x) __builtin_amdgcn_exp2f(x)
#else
#define EXP2(x) exp2f(x)
#endif

// log2(e)/16 — folds the 1/sqrt(256) logit scale AND exp->exp2 into Wq
// (RoPE rotation is linear: scale commutes).
#define QSCALE 0.09016844f

// ===========================================================================
// FRAGMENT-ORDERED GLOBAL LAYOUTS: every MFMA operand fragment
// (64 lanes x 16 B) is stored contiguously, so consumers issue
// perfectly-coalesced global b128 loads with NO LDS staging and NO barriers.
//   W:  wfrag(m, ht, c)        = ((m*4+ht)*8+c)*512    + lane*8
//   Q:  qfrag(rowblk16, half)  = (rowblk*2+half)*512   + lane*8
//   K:  kfrag(kvblk64,mt,half) = ((kvblk*4+mt)*2+half)*512 + lane*8
//   V:  vfrag(kvblk64,hh,half) = ((kvblk*4+hh)*2+half)*512 + lane*8
// (rowblk/kvblk are GLOBAL over B*T; lane = quad*16+l16.)
//
// SESSION WARNINGS (hard-won):
//  * R3: cooperative LDS staging w/ per-tile s_barriers -> attn 15->132 us.
//    Keep the loop barrier-FREE; independent waves hide each other's latency.
//  * R4: __threadfence() (device-scope) in attn -> attn 140 us (L2
//    writeback/invalidate storm).  NO device fences in hot kernels.
//  * R7: XCD-matched combine = neutral (combine was never the bottleneck).
//  * R8 (this round): Ps XOR-swizzle (SQ_LDS_BANK_CONFLICT was 1.57M/
//    dispatch at LDP=72) + s_setprio around MFMA clusters (T5, attn-class
//    verified).  Output bit-identical.
// ===========================================================================

// ---------------------------------------------------------------------------
// Kernel P: W transpose + bf16 cast + fragment-order emit. 12 blocks.
// ---------------------------------------------------------------------------
__global__ __launch_bounds__(256) void prep_w_kernel(
    const float* __restrict__ Wq, const float* __restrict__ Wk,
    const float* __restrict__ Wv, unsigned short* __restrict__ wt) {
  const int m = blockIdx.x >> 2;        // 0..2: which matrix
  const int cp = blockIdx.x & 3;        // c-pair: handles c = cp*2, cp*2+1
  const float* W = (m == 0) ? Wq : (m == 1) ? Wk : Wv;
  const float scale = (m == 0) ? QSCALE : 1.f;
  __shared__ __align__(16) unsigned short tile[64][72];  // [h][d-local]
  int h = threadIdx.x & 63, dq = threadIdx.x >> 6;
  const int d0 = cp * 64;
  for (int dl = dq; dl < 64; dl += 4)
    tile[h][dl] = f2bf(W[(d0 + dl) * H_ + h] * scale);
  __syncthreads();
  int ht = threadIdx.x >> 6;            // wave = ht
  int lane = threadIdx.x & 63, quad = lane >> 4, l16 = lane & 15;
#pragma unroll
  for (int cl = 0; cl < 2; ++cl) {
    int c = cp * 2 + cl;
    bf16x8 v = *(const bf16x8*)&tile[ht * 16 + l16][cl * 32 + quad * 8];
    *(bf16x8*)&wt[(((m * 4 + ht) * 8 + c) << 9) + lane * 8] = v;
  }
}

// ---------------------------------------------------------------------------
// Kernel A: MFMA QKV projection + RoPE, fragment-ordered outputs.
// (unchanged from round 2)
// ---------------------------------------------------------------------------
__global__ __launch_bounds__(192) void qkv_kernel(
    const float* __restrict__ x, const unsigned short* __restrict__ wt,
    const float* __restrict__ axg, const float* __restrict__ ayg,
    unsigned short* __restrict__ qo, unsigned short* __restrict__ ko,
    unsigned short* __restrict__ vt) {
  const int row0g = blockIdx.x * 16;    // global flat row over B*T
  const int tid = threadIdx.x;
  const int w = tid / 64, lane = tid & 63, quad = lane >> 4, l16 = lane & 15;

  __shared__ unsigned short xs[16][264];      // 8.4 KB
  __shared__ unsigned short qkt[2][16][72];   // q/k transpose, per-wave
  __shared__ unsigned short vsh[64][16];      // v transpose (wave 2 only)

  // stage x-tile: 16 rows x 256 f32 = 1024 float4, convert to bf16
  const float4* xb = (const float4*)(x + (size_t)row0g * D_);
  for (int i = tid; i < 1024; i += 192) {
    float4 v = xb[i];
    int r = i >> 6, c4 = (i & 63) << 2;
    *(unsigned int*)&xs[r][c4] = pk2(v.x, v.y);
    *(unsigned int*)&xs[r][c4 + 2] = pk2(v.z, v.w);
  }
  __syncthreads();

  // x fragments: A[m=l16][k=c*32+quad*8+j]
  bf16x8 xf[8];
#pragma unroll
  for (int c = 0; c < 8; ++c)
    xf[c] = *(const bf16x8*)&xs[l16][c * 32 + quad * 8];

  // GEMM for matrix w: W-frags coalesced from global
  const unsigned short* wb = wt + (((size_t)w * 4) * 8 << 9);
  f32x4 acc[4];
#pragma unroll
  for (int ht = 0; ht < 4; ++ht) acc[ht] = (f32x4){0.f, 0.f, 0.f, 0.f};
#pragma unroll
  for (int c = 0; c < 8; ++c) {
#pragma unroll
    for (int ht = 0; ht < 4; ++ht) {
      bf16x8 wf = *(const bf16x8*)&wb[((ht * 8 + c) << 9) + lane * 8];
      acc[ht] = __builtin_amdgcn_mfma_f32_16x16x32_bf16(xf[c], wf, acc[ht],
                                                        0, 0, 0);
    }
  }

  const int row0loc = row0g & (T_ - 1);
  if (w < 2) {
    // RoPE on C/D layout, then LDS transpose -> fragment-order store
    const float sgn = (l16 & 1) ? 1.f : -1.f;
#pragma unroll
    for (int ht = 0; ht < 4; ++ht) {
      int hh = ht * 16 + l16;
      int pidx = (hh & 31) >> 1;
      const float* ab = (hh >= 32) ? ayg : axg;
#pragma unroll
      for (int r = 0; r < 4; ++r) {
        int t = row0loc + quad * 4 + r;
        float s, c;
        __sincosf(ab[t * 16 + pidx], &s, &c);
        float val = acc[ht][r];
        float par = __shfl_xor(val, 1);   // RoPE pair partner h^1
        qkt[w][quad * 4 + r][hh] = f2bf(val * c + sgn * par * s);
      }
    }
    asm volatile("s_waitcnt lgkmcnt(0)" ::: "memory");  // intra-wave
    unsigned short* dst;
    size_t base;
    if (w == 0) {
      dst = qo;
      base = ((size_t)(row0g >> 4) * 2) << 9;
    } else {
      dst = ko;
      base = ((size_t)((row0g >> 6) * 8 + ((row0g >> 4) & 3) * 2)) << 9;
    }
#pragma unroll
    for (int half = 0; half < 2; ++half) {
      bf16x8 v = *(const bf16x8*)&qkt[w][l16][half * 32 + quad * 8];
      *(bf16x8*)&dst[base + half * 512 + lane * 8] = v;
    }
  } else {
    // v: C/D -> LDS transpose -> partial fragment-order store
#pragma unroll
    for (int ht = 0; ht < 4; ++ht)
#pragma unroll
      for (int r = 0; r < 4; ++r)
        vsh[ht * 16 + l16][quad * 4 + r] = f2bf(acc[ht][r]);
    asm volatile("s_waitcnt lgkmcnt(0)" ::: "memory");  // intra-wave
    const int kvblk = row0g >> 6;       // global 64-blk
    const int mt = (row0g >> 4) & 3;
    const int half_v = mt >> 1, qlow = (mt & 1) * 2;
#pragma unroll
    for (int it = 0; it < 2; ++it) {
      int hhx = it * 2 + (quad >> 1);
      int qp = qlow + (quad & 1);
      bf16x8 v = *(const bf16x8*)&vsh[hhx * 16 + l16][(quad & 1) * 8];
      *(bf16x8*)&vt[((((size_t)kvblk * 4 + hhx) * 2 + half_v) << 9) +
                    (qp * 16 + l16) * 8] = v;
    }
  }
}

// ---------------------------------------------------------------------------
// Kernel B: flash attention, split-KV, fixed max (logits bounded; m=0
// softmax is exact math), exp2 domain.  Round-2 barrier-free structure;
// R8 deltas (both output-bit-identical):
//  * Ps: LDP 72 -> 64 (rows are 128 B) + XOR swizzle byte^=((row&7)<<4)
//    on write AND read — the m214-verified T2 recipe for [64][128B] bf16
//    tiles.  Kills the 1.57M/dispatch SQ_LDS_BANK_CONFLICT inside the
//    per-iter lgkmcnt(0) drain.  Also: Ps 36 -> 32 KB.
//  * s_setprio(1)/(0) around the QK^T+exp phase and the PV MFMA cluster
//    (T5): waves at MFMA phases preempt waves issuing loads.
// ---------------------------------------------------------------------------
__global__ __launch_bounds__(256, 2) void attn_kernel(
    const unsigned short* __restrict__ qfg, const unsigned short* __restrict__ kfg,
    const unsigned short* __restrict__ vfg, float* __restrict__ opart,
    float* __restrict__ lpart, int kv_len) {
  const int split = blockIdx.x >> 6;    // 64 blocks per split
  const int rem = blockIdx.x & 63;
  const int b = rem >> 4;
  const int q0 = (rem & 15) * 256;
  const int tid = threadIdx.x;
  const int w = tid >> 6, lane = tid & 63, quad = lane >> 4, l16 = lane & 15;

  __shared__ unsigned short Ps[4][64 * 64];   // per-wave P, 32 KB, swizzled

  // Q fragments (B-operand), coalesced from fragment-ordered qfg
  bf16x8 qf[4][2];
#pragma unroll
  for (int u = 0; u < 4; ++u) {
    size_t rb = (size_t)(b * T_ + q0 + w * 64 + u * 16) >> 4;
#pragma unroll
    for (int half = 0; half < 2; ++half)
      qf[u][half] = *(const bf16x8*)&qfg[((rb * 2 + half) << 9) + lane * 8];
  }

  f32x4 oacc[4][4];
  float lsum[4] = {0.f, 0.f, 0.f, 0.f};
  const f32x4 vzero = {0.f, 0.f, 0.f, 0.f};
#pragma unroll
  for (int u = 0; u < 4; ++u)
#pragma unroll
    for (int hh = 0; hh < 4; ++hh) oacc[u][hh] = vzero;

  const int kvb0 = (b * T_ + split * kv_len) >> 6;
  const int nkvb = kv_len >> 6;

  // prologue: K fragments for tile 0
  bf16x8 kf[8];
  {
    const unsigned short* kfb = kfg + ((size_t)kvb0 << 12);
#pragma unroll
    for (int f = 0; f < 8; ++f)
      kf[f] = *(const bf16x8*)&kfb[(f << 9) + lane * 8];
  }

  for (int kb = 0; kb < nkvb; ++kb) {
    const unsigned short* vfb = vfg + ((size_t)(kvb0 + kb) << 12);
    const int kbn = (kb + 1 < nkvb) ? (kb + 1) : kb;
    const unsigned short* kfb_n = kfg + ((size_t)(kvb0 + kbn) << 12);

    // S^T: D[kv=mt*16+quad*4+r][q=u*16+l16] (log2 domain via QSCALE),
    // exp2 + pack + swizzled LDS write fused per (mt,u).
    __builtin_amdgcn_s_setprio(1);
#pragma unroll
    for (int mt = 0; mt < 4; ++mt) {
#pragma unroll
      for (int u = 0; u < 4; ++u) {
        f32x4 s = vzero;
        s = __builtin_amdgcn_mfma_f32_16x16x32_bf16(kf[mt * 2 + 0], qf[u][0],
                                                    s, 0, 0, 0);
        s = __builtin_amdgcn_mfma_f32_16x16x32_bf16(kf[mt * 2 + 1], qf[u][1],
                                                    s, 0, 0, 0);
        float p0 = EXP2(s[0]);
        float p1 = EXP2(s[1]);
        float p2 = EXP2(s[2]);
        float p3 = EXP2(s[3]);
        lsum[u] += (p0 + p1) + (p2 + p3);
        uint2 pk;
        pk.x = pk2(p0, p1);
        pk.y = pk2(p2, p3);
        int row = u * 16 + l16;
        int colB = (mt * 32 + quad * 8) ^ ((row & 7) << 4);  // T2 swizzle
        *(uint2*)&Ps[w][row * 64 + (colB >> 1)] = pk;
      }
    }
    __builtin_amdgcn_s_setprio(0);

    // issue V loads (current tile) + K prefetch (next tile) BEFORE the LDS
    // drain — vmcnt traffic overlaps the Ps round-trip and PV MFMAs.
    bf16x8 vf[8];
#pragma unroll
    for (int f = 0; f < 8; ++f)
      vf[f] = *(const bf16x8*)&vfb[(f << 9) + lane * 8];
#pragma unroll
    for (int f = 0; f < 8; ++f)
      kf[f] = *(const bf16x8*)&kfb_n[(f << 9) + lane * 8];

    asm volatile("s_waitcnt lgkmcnt(0)" ::: "memory");  // intra-wave Ps

    bf16x8 ap[4][2];
#pragma unroll
    for (int u = 0; u < 4; ++u)
#pragma unroll
      for (int half = 0; half < 2; ++half) {
        int row = u * 16 + l16;
        int colB = (half * 64 + quad * 16) ^ ((row & 7) << 4);  // T2 swizzle
        ap[u][half] = *(const bf16x8*)&Ps[w][row * 64 + (colB >> 1)];
      }

    __builtin_amdgcn_s_setprio(1);
#pragma unroll
    for (int hh = 0; hh < 4; ++hh) {
#pragma unroll
      for (int u = 0; u < 4; ++u) {
        oacc[u][hh] = __builtin_amdgcn_mfma_f32_16x16x32_bf16(
            ap[u][0], vf[hh * 2 + 0], oacc[u][hh], 0, 0, 0);
        oacc[u][hh] = __builtin_amdgcn_mfma_f32_16x16x32_bf16(
            ap[u][1], vf[hh * 2 + 1], oacc[u][hh], 0, 0, 0);
      }
    }
    __builtin_amdgcn_s_setprio(0);
  }

  // epilogue: un-normalized partials; l via lane butterfly (sum over quads)
#pragma unroll
  for (int u = 0; u < 4; ++u) {
    size_t base = (size_t)(split * B_ + b) * T_ + q0 + w * 64 + u * 16;
#pragma unroll
    for (int r = 0; r < 4; ++r) {
      float* orow = opart + (base + quad * 4 + r) * H_;
#pragma unroll
      for (int hh = 0; hh < 4; ++hh) orow[hh * 16 + l16] = oacc[u][hh][r];
    }
    float l = lsum[u];
    l += __shfl_xor(l, 16);
    l += __shfl_xor(l, 32);
    if (quad == 0) lpart[base + l16] = l;   // coalesced 16-wide
  }
}

// ---------------------------------------------------------------------------
// Kernel C: out = (sum_s O_s) / (sum_s l_s).  XCD-matched block mapping
// (R7: measured neutral, kept as harmless).
// ---------------------------------------------------------------------------
__global__ __launch_bounds__(256) void combine_kernel(
    const float* __restrict__ opart, const float* __restrict__ lpart,
    float* __restrict__ out, int ns) {
  const int rem = blockIdx.x & 63;      // chunk, XCD-matched to attn writers
  const int j = blockIdx.x >> 6;        // 0..7: which 32-row part
  const size_t row0 = (size_t)(rem >> 4) * T_ + (rem & 15) * 256 + j * 32;
  const int t = threadIdx.x;
#pragma unroll
  for (int rep = 0; rep < 2; ++rep) {
    int idx = t + rep * 256;            // 0..511 float4s in this part
    int r = idx >> 4, c4 = idx & 15;
    size_t row = row0 + r;
    float den = 0.f;
    float ax = 0.f, ay = 0.f, az = 0.f, aw = 0.f;
    for (int s = 0; s < ns; ++s) {
      den += lpart[(size_t)s * NBT + row];
      float4 o = *(const float4*)&opart[((size_t)s * NBT + row) * H_ + c4 * 4];
      ax += o.x; ay += o.y; az += o.z; aw += o.w;
    }
    float inv = 1.f / den;
    float4 res;
    res.x = ax * inv; res.y = ay * inv; res.z = az * inv; res.w = aw * inv;
    *(float4*)&out[row * H_ + c4 * 4] = res;
  }
}

// ---------------------------------------------------------------------------
extern "C" void kernel_launch(void* const* d_in, const int* in_sizes, int n_in,
                              void* d_out, int out_size, void* d_ws,
                              size_t ws_size, hipStream_t stream) {
  const float* x  = (const float*)d_in[0];
  const float* Wq = (const float*)d_in[1];
  const float* Wk = (const float*)d_in[2];
  const float* Wv = (const float*)d_in[3];
  const float* ax = (const float*)d_in[4];
  const float* ay = (const float*)d_in[5];
  float* out = (float*)d_out;

  // ws: q|k|v frag-ordered bf16 (6MB) | wt bf16 (96KB) | opart | lpart
  unsigned short* qo = (unsigned short*)d_ws;
  unsigned short* ko = qo + NBTH;
  unsigned short* vt = ko + NBTH;
  unsigned short* wt = vt + NBTH;
  float* opart = (float*)(wt + 3 * H_ * D_);

  size_t fixed = (size_t)3 * NBTH * 2 + (size_t)3 * H_ * D_ * 2;
  int NS = (ws_size >= fixed + (size_t)8 * NBTH * 4 + (size_t)8 * NBT * 4 + 256)
               ? 8 : 4;
  float* lpart = opart + (size_t)NS * NBTH;

  prep_w_kernel<<<12, 256, 0, stream>>>(Wq, Wk, Wv, wt);
  qkv_kernel<<<NBT / 16, 192, 0, stream>>>(x, wt, ax, ay, qo, ko, vt);
  attn_kernel<<<NS * 64, 256, 0, stream>>>(qo, ko, vt, opart, lpart, T_ / NS);
  combine_kernel<<<512, 256, 0, stream>>>(opart, lpart, out, NS);
}